// Round 4
// baseline (279.922 us; speedup 1.0000x reference)
//
#include <hip/hip_runtime.h>
#include <math.h>

// SparseGate: B=16384, D=2048, E=64, k=2
// R4: fuse gemm+combine into one full-K kernel (no split-K, no part buffer).
//   pipeline: wprep (1 MB bpk pack) -> fused gemm+gate -> recheck.
//   Removes 64 MB part round-trip + 1 launch + 1 graph gap vs R3 (259.8 us).
// Fragment conventions identical to the verified R3 kernel:
//   A/B: lane l -> row/col = l&15, k = (l>>4)*8 + j   (16x16x32 bf16)
//   C/D: col = l&15, row = (l>>4)*4 + reg
//   3-pass bf16 emulation: hi*bh + hi*bl + lo*bh
#define NROWS 16384
#define DDIM  2048
#define NEXP  64
#define NCOL  128            // fused: 64 gate cols + 64 noise cols

constexpr float TAU = 1e-3f;        // margin below which we recheck in fp32

typedef __attribute__((ext_vector_type(8))) short short8;
typedef __attribute__((ext_vector_type(4))) float floatx4;

// ---------------- fp32 -> bf16 hi/lo truncation split ----------------
__device__ __forceinline__ void split8(const float4 a, const float4 b,
                                       short8* hi, short8* lo)
{
    float f[8] = {a.x, a.y, a.z, a.w, b.x, b.y, b.z, b.w};
    union { unsigned short u[8]; short8 v; } H, L;
    #pragma unroll
    for (int j = 0; j < 8; ++j) {
        const unsigned int u  = __float_as_uint(f[j]);
        const unsigned int hf = u & 0xFFFF0000u;
        const float lf = f[j] - __uint_as_float(hf);   // exact
        H.u[j] = (unsigned short)(u >> 16);
        L.u[j] = (unsigned short)(__float_as_uint(lf) >> 16);
    }
    *hi = H.v; *lo = L.v;
}

__device__ __forceinline__ float softplus_f(float x) {
    return fmaxf(x, 0.f) + log1pf(expf(-fabsf(x)));
}

// ---------------- top-k + softmax over a 64-lane row ----------------
__device__ __forceinline__ float row_gate(int lane, float ew, int k, float* margin)
{
    float cur = ew;
    const float myv = ew;
    float m0 = 0.f, denom = 0.f, vk = 0.f, vk1 = 0.f;
    int selected = 0;
    const int iters = (k < NEXP) ? (k + 1) : k;
    for (int t = 0; t < iters; ++t) {
        float v = cur;
        int idx = lane;
        #pragma unroll
        for (int off = 32; off; off >>= 1) {
            const float ov = __shfl_xor(v, off);
            const int   oi = __shfl_xor(idx, off);
            if (ov > v || (ov == v && oi < idx)) { v = ov; idx = oi; }
        }
        if (t == 0) m0 = v;
        if (t < k) {
            denom += expf(v - m0);
            vk = v;
            if (lane == idx) { selected = 1; cur = -INFINITY; }
        } else {
            vk1 = v;
        }
    }
    *margin = (k < NEXP) ? (vk - vk1) : 1e30f;
    return selected ? expf(myv - m0) / denom : 0.f;
}

// ---------------- weight prep: pack B in exact wave-read order ----------------
// UNCHANGED from R3 (verified). Bpk short index:
//   (((kt*8 + ct)*2 + h)*64 + ln)*8 + j   (1 MB total)
// value = bf16 part h of W[col = ct*16 + (ln&15)][k = kt*32 + (ln>>4)*8 + j]
__global__ __launch_bounds__(256) void wprep_kernel(
    const float* __restrict__ gw, const float* __restrict__ nw,
    unsigned short* __restrict__ bpk, int* __restrict__ counter)
{
    const int g = blockIdx.x * 256 + threadIdx.x;    // 0..32767
    if (g == 0) counter[0] = 0;
    const int kt = g >> 9;            // 0..63
    const int ct = (g >> 6) & 7;      // 0..7
    const int ln = g & 63;            // 0..63
    const int col = ct * 16 + (ln & 15);
    const int kb  = kt * 32 + (ln >> 4) * 8;
    const float* src = (col < NEXP) ? (gw + (size_t)col * DDIM)
                                    : (nw + (size_t)(col - NEXP) * DDIM);
    src += kb;
    const float4 a = *(const float4*)src;
    const float4 b = *(const float4*)(src + 4);
    short8 hi, lo;
    split8(a, b, &hi, &lo);
    const size_t base = ((size_t)(kt * 8 + ct) * 2) * 512 + (size_t)ln * 8;
    *(short8*)&bpk[base]       = hi;    // h=0
    *(short8*)&bpk[base + 512] = lo;    // h=1
}

// ---------------- fused full-K GEMM + gate ----------------
// Block = 16 rows x 128 cols x K=2048; 256 threads = 4 waves, each wave
// owns 16 rows x 32 cols (2 ct of 16). 32 iterations of 64-k:
//   stage A (128 threads, fp32->bf16 hi/lo, ds_write_b128, double-buffered)
//   -> barrier -> 2 k-steps x {2 ds_read_b128 A-frags, 2 ct x 3 MFMA},
//   B fragments register-double-buffered one full iteration ahead (L2-hot).
// Epilogue: acc -> LDS ew[16][128] -> per-wave row_gate on 4 rows -> out.
__global__ __launch_bounds__(256, 4) void fused_kernel(
    const float* __restrict__ x,
    const unsigned short* __restrict__ bpk,
    const float* __restrict__ noise,
    const int* __restrict__ kptr,
    float* __restrict__ out,
    int* __restrict__ counter,
    int* __restrict__ list)
{
    // [buf][h][ks][kq][row][8 shorts] = 16 KB.
    // write: lanes = (row 0..7)x(kblk 0..7): bank group = row -> 8 lanes/group
    //        (balanced b128 floor). read (h,ks fixed): 16 lanes -> 16
    //        contiguous 16B chunks (proven-free pattern).
    __shared__ __align__(16) unsigned short ldsA[2][2][2][4][16][8];
    __shared__ float ew[16][NCOL];   // 8 KB logits exchange

    const int tid  = threadIdx.x;
    const int wv   = tid >> 6;
    const int ln   = tid & 63;
    const int l15  = ln & 15;
    const int quad = ln >> 4;

    const int rowbase = blockIdx.x * 16;         // grid.x = 1024

    // staging assignment (tid < 128): row = tid>>3, k-block = (tid&7)*8
    const int srow = tid >> 3;
    const int skb  = (tid & 7) * 8;
    const int sks  = skb >> 5;
    const int skq  = (skb >> 3) & 3;
    const float* xs = x + (size_t)(rowbase + srow) * DDIM + skb;

    const short8* bp = (const short8*)bpk;       // idx = ((kt*8+ct)*2+h)*64 + ln
    const int ctg0 = wv * 2;                     // this wave's first col-16 tile

    floatx4 acc[2];
    acc[0] = (floatx4){0.f, 0.f, 0.f, 0.f};
    acc[1] = (floatx4){0.f, 0.f, 0.f, 0.f};

    // preamble: A(it=0) regs; B for it=0 (kt 0,1) into bX
    float4 ar0 = {0.f, 0.f, 0.f, 0.f};
    float4 ar1 = {0.f, 0.f, 0.f, 0.f};
    if (tid < 128) {
        ar0 = *(const float4*)(xs);
        ar1 = *(const float4*)(xs + 4);
    }
    short8 bX[2][2][2], bY[2][2][2];             // [ks][ct][h]
    #pragma unroll
    for (int ks = 0; ks < 2; ++ks)
        #pragma unroll
        for (int ct = 0; ct < 2; ++ct) {
            bX[ks][ct][0] = bp[(size_t)((ks * 8 + ctg0 + ct) * 2 + 0) * 64 + ln];
            bX[ks][ct][1] = bp[(size_t)((ks * 8 + ctg0 + ct) * 2 + 1) * 64 + ln];
        }

    // one 64-k iteration: stage A(it), barrier, prefetch A(it+1),
    // 2 k-steps of MFMA consuming bc, prefetching bn for it+1.
    #define FUSED_ITER(it, buf, bc, bn, PREF)                                      \
    {                                                                              \
        if (tid < 128) {                                                           \
            short8 hi, lo;                                                         \
            split8(ar0, ar1, &hi, &lo);                                            \
            *(short8*)&ldsA[buf][0][sks][skq][srow][0] = hi;                       \
            *(short8*)&ldsA[buf][1][sks][skq][srow][0] = lo;                       \
        }                                                                          \
        __syncthreads();                                                           \
        if (tid < 128 && (it) + 1 < 32) {                                          \
            const float* xn = xs + ((it) + 1) * 64;                                \
            ar0 = *(const float4*)(xn);                                            \
            ar1 = *(const float4*)(xn + 4);                                        \
        }                                                                          \
        _Pragma("unroll")                                                          \
        for (int ks = 0; ks < 2; ++ks) {                                           \
            const short8 Ah = *(const short8*)&ldsA[buf][0][ks][quad][l15][0];     \
            const short8 Al = *(const short8*)&ldsA[buf][1][ks][quad][l15][0];     \
            const int ktn = ((it) + 1) * 2 + ks;                                   \
            _Pragma("unroll")                                                      \
            for (int ct = 0; ct < 2; ++ct) {                                       \
                if (PREF) {                                                        \
                    bn[ks][ct][0] = bp[(size_t)((ktn * 8 + ctg0 + ct) * 2 + 0) * 64 + ln]; \
                    bn[ks][ct][1] = bp[(size_t)((ktn * 8 + ctg0 + ct) * 2 + 1) * 64 + ln]; \
                }                                                                  \
                const short8 bh = bc[ks][ct][0];                                   \
                const short8 bl = bc[ks][ct][1];                                   \
                acc[ct] = __builtin_amdgcn_mfma_f32_16x16x32_bf16(Ah, bh, acc[ct], 0, 0, 0); \
                acc[ct] = __builtin_amdgcn_mfma_f32_16x16x32_bf16(Ah, bl, acc[ct], 0, 0, 0); \
                acc[ct] = __builtin_amdgcn_mfma_f32_16x16x32_bf16(Al, bh, acc[ct], 0, 0, 0); \
            }                                                                      \
        }                                                                          \
    }

    for (int m = 0; m < 16; ++m) {
        FUSED_ITER(2 * m,     0, bX, bY, 1)
        FUSED_ITER(2 * m + 1, 1, bY, bX, (m < 15))
    }
    #undef FUSED_ITER

    // ---- epilogue: acc -> ew LDS (C/D: col=l15, row=quad*4+r) ----
    #pragma unroll
    for (int ct = 0; ct < 2; ++ct) {
        const int col = (ctg0 + ct) * 16 + l15;
        #pragma unroll
        for (int r = 0; r < 4; ++r)
            ew[quad * 4 + r][col] = acc[ct][r];
    }
    __syncthreads();

    int k = kptr[0];
    if (k < 1) k = 1;
    if (k > NEXP) k = NEXP;

    // each wave gates 4 rows (64 lanes = 64 experts)
    #pragma unroll
    for (int rr = 0; rr < 4; ++rr) {
        const int row  = wv * 4 + rr;
        const int grow = rowbase + row;
        const float clean = ew[row][ln];
        const float noisy = ew[row][NEXP + ln];
        const float nz    = noise[(size_t)grow * NEXP + ln];
        const float ewv   = clean + nz * softplus_f(noisy);
        float margin;
        const float val = row_gate(ln, ewv, k, &margin);
        out[(size_t)grow * NEXP + ln] = val;
        if (margin < TAU && ln == 0) {
            const int pos = atomicAdd(counter, 1);
            list[pos] = grow;
        }
    }
}

// ---------------- exact fp32 recheck for low-margin rows ----------------
__global__ __launch_bounds__(256) void recheck_kernel(
    const float* __restrict__ x,
    const float* __restrict__ gw,
    const float* __restrict__ nw,
    const float* __restrict__ noise,
    const int* __restrict__ kptr,
    float* __restrict__ out,
    const int* __restrict__ counter,
    const int* __restrict__ list)
{
    __shared__ float xr[DDIM];      // 8 KB
    __shared__ float parts[256];
    __shared__ float lg[NCOL];

    const int tid = threadIdx.x;
    const int cnt = counter[0];

    int k = kptr[0];
    if (k < 1) k = 1;
    if (k > NEXP) k = NEXP;

    for (int ii = blockIdx.x; ii < cnt; ii += gridDim.x) {
        const int row = list[ii];
        const float4* xs = (const float4*)(x + (size_t)row * DDIM);
        #pragma unroll
        for (int j = 0; j < 2; ++j)
            ((float4*)xr)[tid + j * 256] = xs[tid + j * 256];
        __syncthreads();

        const int e = tid & 127;
        const int half = tid >> 7;
        const float* wc = (e < NEXP) ? (gw + (size_t)e * DDIM)
                                     : (nw + (size_t)(e - NEXP) * DDIM);
        wc += half * 1024;
        const float* xc = xr + half * 1024;
        float s = 0.f;
        #pragma unroll 4
        for (int j = 0; j < 1024; j += 4) {
            float4 w4 = *(const float4*)&wc[j];
            s += xc[j] * w4.x + xc[j + 1] * w4.y + xc[j + 2] * w4.z + xc[j + 3] * w4.w;
        }
        parts[tid] = s;
        __syncthreads();
        if (tid < NCOL) lg[tid] = parts[tid] + parts[tid + 128];
        __syncthreads();
        if (tid < NEXP) {
            const float ew = lg[tid] + noise[(size_t)row * NEXP + tid] * softplus_f(lg[NEXP + tid]);
            float margin;
            const float val = row_gate(tid, ew, k, &margin);
            out[(size_t)row * NEXP + tid] = val;
        }
        __syncthreads();
    }
}

// ---------------- fallback: exact per-row (only if ws too small) ----------------
__global__ __launch_bounds__(256) void naive_kernel(
    const float* __restrict__ x,
    const float* __restrict__ gw,
    const float* __restrict__ nw,
    const float* __restrict__ noise,
    const int* __restrict__ kptr,
    float* __restrict__ out)
{
    const int lane = threadIdx.x & 63;
    const int wave = threadIdx.x >> 6;
    const int row  = blockIdx.x * 4 + wave;
    if (row >= NROWS) return;

    int k = kptr[0];
    if (k < 1) k = 1;
    if (k > NEXP) k = NEXP;

    const float* xr = x  + (size_t)row  * DDIM;
    const float* g  = gw + (size_t)lane * DDIM;
    const float* w2 = nw + (size_t)lane * DDIM;
    float c = 0.f, n = 0.f;
    for (int d = 0; d < DDIM; ++d) {
        const float xv = xr[d];
        c += xv * g[d];
        n += xv * w2[d];
    }
    const float ew = c + noise[(size_t)row * NEXP + lane] * softplus_f(n);
    float margin;
    out[(size_t)row * NEXP + lane] = row_gate(lane, ew, k, &margin);
}

// ---------------------------------------------------------------------------
extern "C" void kernel_launch(void* const* d_in, const int* in_sizes, int n_in,
                              void* d_out, int out_size, void* d_ws, size_t ws_size,
                              hipStream_t stream)
{
    const float* x     = (const float*)d_in[0];
    const float* gw    = (const float*)d_in[1];
    const float* nw    = (const float*)d_in[2];
    const float* noise = (const float*)d_in[3];
    const int*   kptr  = (const int*)d_in[4];
    float* out = (float*)d_out;

    // ws: bpk (1 MB) | counter (256 B) | list (64 KB)
    const size_t BPK_BYTES = (size_t)NCOL * DDIM * 2 * sizeof(unsigned short); // 1 MB
    const size_t TAIL      = 256 + NROWS * sizeof(int);

    if (ws_size < BPK_BYTES + TAIL) {
        hipLaunchKernelGGL(naive_kernel, dim3(NROWS / 4), dim3(256), 0, stream,
                           x, gw, nw, noise, kptr, out);
        return;
    }

    unsigned short* bpk     = (unsigned short*)d_ws;
    int*            counter = (int*)((char*)d_ws + BPK_BYTES);
    int*            list    = counter + 64;

    hipLaunchKernelGGL(wprep_kernel, dim3(128), dim3(256), 0, stream,
                       gw, nw, bpk, counter);
    hipLaunchKernelGGL(fused_kernel, dim3(NROWS / 16), dim3(256), 0, stream,
                       x, bpk, noise, kptr, out, counter, list);
    hipLaunchKernelGGL(recheck_kernel, dim3(256), dim3(256), 0, stream,
                       x, gw, nw, noise, kptr, out, counter, list);
}

// Round 5
// 252.802 us; speedup vs baseline: 1.1073x; 1.1073x over previous
//
#include <hip/hip_runtime.h>
#include <math.h>

// SparseGate: B=16384, D=2048, E=64, k=2
// R5: in-block split-K. One 1024-thread block = 4 K-groups x 4 waves; each
// K-group runs the verified R3 gemm inner loop (64 rows x 128 cols x 512 k,
// wave = 32x64, depth-1 B prefetch) on its K-quarter with private LDS
// staging. Partials reduced via LDS (4 phased adds), gate fused in-block.
//   vs R3: deletes part buffer (64 MB HBM round-trip), combine kernel, 1 gap.
//   vs R4: restores 64-row tiles -> B-L2 traffic 1 GB -> 256 MB (the measured
//          latency wall: MfmaUtil 10%, VALU 16%, HBM 10%, VGPR_Count=44
//          proved B prefetch was demoted; R3's reuse-in-place pattern kept).
#define NROWS 16384
#define DDIM  2048
#define NEXP  64
#define NCOL  128            // fused: 64 gate cols + 64 noise cols

constexpr float TAU = 1e-3f;        // margin below which we recheck in fp32

typedef __attribute__((ext_vector_type(8))) short short8;
typedef __attribute__((ext_vector_type(4))) float floatx4;

// ---------------- fp32 -> bf16 hi/lo truncation split ----------------
__device__ __forceinline__ void split8(const float4 a, const float4 b,
                                       short8* hi, short8* lo)
{
    float f[8] = {a.x, a.y, a.z, a.w, b.x, b.y, b.z, b.w};
    union { unsigned short u[8]; short8 v; } H, L;
    #pragma unroll
    for (int j = 0; j < 8; ++j) {
        const unsigned int u  = __float_as_uint(f[j]);
        const unsigned int hf = u & 0xFFFF0000u;
        const float lf = f[j] - __uint_as_float(hf);   // exact
        H.u[j] = (unsigned short)(u >> 16);
        L.u[j] = (unsigned short)(__float_as_uint(lf) >> 16);
    }
    *hi = H.v; *lo = L.v;
}

__device__ __forceinline__ float softplus_f(float x) {
    return fmaxf(x, 0.f) + log1pf(expf(-fabsf(x)));
}

// ---------------- top-k + softmax over a 64-lane row ----------------
__device__ __forceinline__ float row_gate(int lane, float ew, int k, float* margin)
{
    float cur = ew;
    const float myv = ew;
    float m0 = 0.f, denom = 0.f, vk = 0.f, vk1 = 0.f;
    int selected = 0;
    const int iters = (k < NEXP) ? (k + 1) : k;
    for (int t = 0; t < iters; ++t) {
        float v = cur;
        int idx = lane;
        #pragma unroll
        for (int off = 32; off; off >>= 1) {
            const float ov = __shfl_xor(v, off);
            const int   oi = __shfl_xor(idx, off);
            if (ov > v || (ov == v && oi < idx)) { v = ov; idx = oi; }
        }
        if (t == 0) m0 = v;
        if (t < k) {
            denom += expf(v - m0);
            vk = v;
            if (lane == idx) { selected = 1; cur = -INFINITY; }
        } else {
            vk1 = v;
        }
    }
    *margin = (k < NEXP) ? (vk - vk1) : 1e30f;
    return selected ? expf(myv - m0) / denom : 0.f;
}

// ---------------- weight prep: pack B in exact wave-read order ----------------
// UNCHANGED (verified). Bpk short index:
//   (((kt*8 + ct)*2 + h)*64 + ln)*8 + j   (1 MB total)
// value = bf16 part h of W[col = ct*16 + (ln&15)][k = kt*32 + (ln>>4)*8 + j]
__global__ __launch_bounds__(256) void wprep_kernel(
    const float* __restrict__ gw, const float* __restrict__ nw,
    unsigned short* __restrict__ bpk, int* __restrict__ counter)
{
    const int g = blockIdx.x * 256 + threadIdx.x;    // 0..32767
    if (g == 0) counter[0] = 0;
    const int kt = g >> 9;            // 0..63
    const int ct = (g >> 6) & 7;      // 0..7
    const int ln = g & 63;            // 0..63
    const int col = ct * 16 + (ln & 15);
    const int kb  = kt * 32 + (ln >> 4) * 8;
    const float* src = (col < NEXP) ? (gw + (size_t)col * DDIM)
                                    : (nw + (size_t)(col - NEXP) * DDIM);
    src += kb;
    const float4 a = *(const float4*)src;
    const float4 b = *(const float4*)(src + 4);
    short8 hi, lo;
    split8(a, b, &hi, &lo);
    const size_t base = ((size_t)(kt * 8 + ct) * 2) * 512 + (size_t)ln * 8;
    *(short8*)&bpk[base]       = hi;    // h=0
    *(short8*)&bpk[base + 512] = lo;    // h=1
}

// ---------------- fused in-block-split-K GEMM + gate ----------------
// Block = 64 rows x 128 cols x K=2048, 1024 threads = 16 waves:
//   kg = wid>>2 (K-quarter, 512 k), wv = wid&3 (R3 wave tile: 32 rows x 64
//   cols, acc[2][4], 24 MFMA / 32-k iter, depth-1 B prefetch reused in place).
// Each kg has a private R3-style double-buffered A staging (16 KB).
// Epilogue: 4 phased LDS adds -> ew[64][128] -> per-wave gate on 4 rows.
__global__ __launch_bounds__(1024, 4) void fused64_kernel(
    const float* __restrict__ x,
    const unsigned short* __restrict__ bpk,
    const float* __restrict__ noise,
    const int* __restrict__ kptr,
    float* __restrict__ out,
    int* __restrict__ counter,
    int* __restrict__ list)
{
    // per-kg layout identical to R3's verified [buf][quad][h][row][8]
    __shared__ __align__(16) unsigned short ldsA[4][2][4][2][64][8];  // 64 KB
    __shared__ float ew[64][NCOL];                                    // 32 KB

    const int tid  = threadIdx.x;
    const int wid  = tid >> 6;          // 0..15
    const int kg   = wid >> 2;          // K-quarter 0..3
    const int wv   = wid & 3;           // wave within kg (R3 role)
    const int ln   = tid & 63;
    const int l15  = ln & 15;
    const int quad = ln >> 4;

    const int rowbase = blockIdx.x * 64;         // grid.x = 256

    // staging assignment within kg's 256 threads (verbatim R3):
    //   st_r = (tid>>2)&63 (64 rows), st_q = tid&3
    const int st_r = (tid >> 2) & 63;
    const int st_q = tid & 3;
    const float* xs = x + (size_t)(rowbase + st_r) * DDIM + kg * 512 + st_q * 8;

    // wave tile (verbatim R3)
    const int rh     = (wv >> 1) * 32;           // row half
    const int ctbase = (wv & 1) * 4;             // col quarter base (4 ct's)

    const short8* bp = (const short8*)bpk;       // idx = ((kt*8+ct)*2+h)*64 + ln
    const int kt0 = kg * 16;                     // this kg's first 32-k slice

    floatx4 acc[2][4];
    #pragma unroll
    for (int rt = 0; rt < 2; ++rt)
        #pragma unroll
        for (int ct = 0; ct < 4; ++ct)
            acc[rt][ct] = (floatx4){0.f, 0.f, 0.f, 0.f};

    // preamble: A(0) regs, B(0) regs
    float4 ar0 = *(const float4*)(xs);
    float4 ar1 = *(const float4*)(xs + 4);
    short8 bcur[4][2];
    #pragma unroll
    for (int ct = 0; ct < 4; ++ct) {
        bcur[ct][0] = bp[(size_t)((kt0 * 8 + ctbase + ct) * 2 + 0) * 64 + ln];
        bcur[ct][1] = bp[(size_t)((kt0 * 8 + ctbase + ct) * 2 + 1) * 64 + ln];
    }

    constexpr int kit = 16;                      // 16 x 32-k = 512 k per kg
    for (int kt = 0; kt < kit; ++kt) {
        const int buf = kt & 1;
        // ---- stage A(kt): consume regs, convert, LDS write ----
        {
            short8 hi, lo;
            split8(ar0, ar1, &hi, &lo);
            *(short8*)&ldsA[kg][buf][st_q][0][st_r][0] = hi;
            *(short8*)&ldsA[kg][buf][st_q][1][st_r][0] = lo;
        }
        __syncthreads();   // all 16 waves in lockstep; dbuf isolates readers

        // ---- issue A(kt+1) now (flies during MFMA phase) ----
        if (kt + 1 < kit) {
            const float* xn = xs + (kt + 1) * 32;
            ar0 = *(const float4*)(xn);
            ar1 = *(const float4*)(xn + 4);
        }

        // ---- A fragments from LDS ----
        short8 ahi[2], alo[2];
        #pragma unroll
        for (int rt = 0; rt < 2; ++rt) {
            const int row = rh + rt * 16 + l15;
            ahi[rt] = *(const short8*)&ldsA[kg][buf][quad][0][row][0];
            alo[rt] = *(const short8*)&ldsA[kg][buf][quad][1][row][0];
        }

        // ---- MFMA: consume bcur, prefetch B(kt+1) per-ct ----
        const int ktg = kt0 + kt;
        #pragma unroll
        for (int ct = 0; ct < 4; ++ct) {
            const short8 bh = bcur[ct][0];
            const short8 bl = bcur[ct][1];
            if (kt + 1 < kit) {
                bcur[ct][0] = bp[(size_t)(((ktg + 1) * 8 + ctbase + ct) * 2 + 0) * 64 + ln];
                bcur[ct][1] = bp[(size_t)(((ktg + 1) * 8 + ctbase + ct) * 2 + 1) * 64 + ln];
            }
            acc[0][ct] = __builtin_amdgcn_mfma_f32_16x16x32_bf16(ahi[0], bh, acc[0][ct], 0, 0, 0);
            acc[1][ct] = __builtin_amdgcn_mfma_f32_16x16x32_bf16(ahi[1], bh, acc[1][ct], 0, 0, 0);
            acc[0][ct] = __builtin_amdgcn_mfma_f32_16x16x32_bf16(ahi[0], bl, acc[0][ct], 0, 0, 0);
            acc[1][ct] = __builtin_amdgcn_mfma_f32_16x16x32_bf16(ahi[1], bl, acc[1][ct], 0, 0, 0);
            acc[0][ct] = __builtin_amdgcn_mfma_f32_16x16x32_bf16(alo[0], bh, acc[0][ct], 0, 0, 0);
            acc[1][ct] = __builtin_amdgcn_mfma_f32_16x16x32_bf16(alo[1], bh, acc[1][ct], 0, 0, 0);
        }
    }

    // ---- phased partial reduce into ew (C/D: col=lane15, row=quad*4+reg) ----
    __syncthreads();   // last LDS reads done before ew overlaps usage pattern
    #pragma unroll
    for (int p = 0; p < 4; ++p) {
        if (kg == p) {
            #pragma unroll
            for (int rt = 0; rt < 2; ++rt)
                #pragma unroll
                for (int r = 0; r < 4; ++r) {
                    const int row = rh + rt * 16 + quad * 4 + r;
                    float* rowp = &ew[row][(wv & 1) * 64 + l15];
                    #pragma unroll
                    for (int ct = 0; ct < 4; ++ct) {
                        if (p == 0) rowp[ct * 16]  = acc[rt][ct][r];
                        else        rowp[ct * 16] += acc[rt][ct][r];
                    }
                }
        }
        __syncthreads();
    }

    // ---- gate: 16 waves x 4 rows each ----
    int k = kptr[0];
    if (k < 1) k = 1;
    if (k > NEXP) k = NEXP;

    #pragma unroll
    for (int rr = 0; rr < 4; ++rr) {
        const int row  = wid * 4 + rr;
        const int grow = rowbase + row;
        const float clean = ew[row][ln];
        const float noisy = ew[row][NEXP + ln];
        const float nz    = noise[(size_t)grow * NEXP + ln];
        const float ewv   = clean + nz * softplus_f(noisy);
        float margin;
        const float val = row_gate(ln, ewv, k, &margin);
        out[(size_t)grow * NEXP + ln] = val;
        if (margin < TAU && ln == 0) {
            const int pos = atomicAdd(counter, 1);
            list[pos] = grow;
        }
    }
}

// ---------------- exact fp32 recheck for low-margin rows ----------------
__global__ __launch_bounds__(256) void recheck_kernel(
    const float* __restrict__ x,
    const float* __restrict__ gw,
    const float* __restrict__ nw,
    const float* __restrict__ noise,
    const int* __restrict__ kptr,
    float* __restrict__ out,
    const int* __restrict__ counter,
    const int* __restrict__ list)
{
    __shared__ float xr[DDIM];      // 8 KB
    __shared__ float parts[256];
    __shared__ float lg[NCOL];

    const int tid = threadIdx.x;
    const int cnt = counter[0];

    int k = kptr[0];
    if (k < 1) k = 1;
    if (k > NEXP) k = NEXP;

    for (int ii = blockIdx.x; ii < cnt; ii += gridDim.x) {
        const int row = list[ii];
        const float4* xs = (const float4*)(x + (size_t)row * DDIM);
        #pragma unroll
        for (int j = 0; j < 2; ++j)
            ((float4*)xr)[tid + j * 256] = xs[tid + j * 256];
        __syncthreads();

        const int e = tid & 127;
        const int half = tid >> 7;
        const float* wc = (e < NEXP) ? (gw + (size_t)e * DDIM)
                                     : (nw + (size_t)(e - NEXP) * DDIM);
        wc += half * 1024;
        const float* xc = xr + half * 1024;
        float s = 0.f;
        #pragma unroll 4
        for (int j = 0; j < 1024; j += 4) {
            float4 w4 = *(const float4*)&wc[j];
            s += xc[j] * w4.x + xc[j + 1] * w4.y + xc[j + 2] * w4.z + xc[j + 3] * w4.w;
        }
        parts[tid] = s;
        __syncthreads();
        if (tid < NCOL) lg[tid] = parts[tid] + parts[tid + 128];
        __syncthreads();
        if (tid < NEXP) {
            const float ew = lg[tid] + noise[(size_t)row * NEXP + tid] * softplus_f(lg[NEXP + tid]);
            float margin;
            const float val = row_gate(tid, ew, k, &margin);
            out[(size_t)row * NEXP + tid] = val;
        }
        __syncthreads();
    }
}

// ---------------- fallback: exact per-row (only if ws too small) ----------------
__global__ __launch_bounds__(256) void naive_kernel(
    const float* __restrict__ x,
    const float* __restrict__ gw,
    const float* __restrict__ nw,
    const float* __restrict__ noise,
    const int* __restrict__ kptr,
    float* __restrict__ out)
{
    const int lane = threadIdx.x & 63;
    const int wave = threadIdx.x >> 6;
    const int row  = blockIdx.x * 4 + wave;
    if (row >= NROWS) return;

    int k = kptr[0];
    if (k < 1) k = 1;
    if (k > NEXP) k = NEXP;

    const float* xr = x  + (size_t)row  * DDIM;
    const float* g  = gw + (size_t)lane * DDIM;
    const float* w2 = nw + (size_t)lane * DDIM;
    float c = 0.f, n = 0.f;
    for (int d = 0; d < DDIM; ++d) {
        const float xv = xr[d];
        c += xv * g[d];
        n += xv * w2[d];
    }
    const float ew = c + noise[(size_t)row * NEXP + lane] * softplus_f(n);
    float margin;
    out[(size_t)row * NEXP + lane] = row_gate(lane, ew, k, &margin);
}

// ---------------------------------------------------------------------------
extern "C" void kernel_launch(void* const* d_in, const int* in_sizes, int n_in,
                              void* d_out, int out_size, void* d_ws, size_t ws_size,
                              hipStream_t stream)
{
    const float* x     = (const float*)d_in[0];
    const float* gw    = (const float*)d_in[1];
    const float* nw    = (const float*)d_in[2];
    const float* noise = (const float*)d_in[3];
    const int*   kptr  = (const int*)d_in[4];
    float* out = (float*)d_out;

    // ws: bpk (1 MB) | counter (256 B) | list (64 KB)
    const size_t BPK_BYTES = (size_t)NCOL * DDIM * 2 * sizeof(unsigned short); // 1 MB
    const size_t TAIL      = 256 + NROWS * sizeof(int);

    if (ws_size < BPK_BYTES + TAIL) {
        hipLaunchKernelGGL(naive_kernel, dim3(NROWS / 4), dim3(256), 0, stream,
                           x, gw, nw, noise, kptr, out);
        return;
    }

    unsigned short* bpk     = (unsigned short*)d_ws;
    int*            counter = (int*)((char*)d_ws + BPK_BYTES);
    int*            list    = counter + 64;

    hipLaunchKernelGGL(wprep_kernel, dim3(128), dim3(256), 0, stream,
                       gw, nw, bpk, counter);
    hipLaunchKernelGGL(fused64_kernel, dim3(NROWS / 64), dim3(1024), 0, stream,
                       x, bpk, noise, kptr, out, counter, list);
    hipLaunchKernelGGL(recheck_kernel, dim3(256), dim3(256), 0, stream,
                       x, gw, nw, noise, kptr, out, counter, list);
}